// Round 2
// baseline (85.845 us; speedup 1.0000x reference)
//
#include <hip/hip_runtime.h>
#include <stdint.h>

// Segmented kNN graph: M=65536 pts, D=16, 64 segments x 1024 pts, K=16.
// Output: int32 src[M*16] then int32 dst[M*16].
//
// v11 = v10 with the launch-bounds spill fixed. v10's __launch_bounds__(1024,4)
// was read with CUDA semantics (min 4 BLOCKS/CU = 64 waves/CU) -> 32-VGPR cap
// -> A/P/R arrays spilled to scratch (rocprof: VGPR_Count=32, WRITE_SIZE
// 31.7MB vs 8MB output, VALUBusy 0.5%). (1024,1) = 16 waves/CU = 4 waves/EU
// -> 128-VGPR cap; live set (~90) fits. Same occupancy as v9 (4x256x4).
//
// Carried from v10: quad-id keys (f32 quad-min via min3+min, tagged with 8-bit
// quad id); repair evaluates all 4 members of each winning quad (R exactly
// full -> final top-16 = top-16 of R, no final keep16). iter-0 A=sorted(P).
// 1024-thread blocks, 256 queries/block, grid=256: staging /4 vs v9; norms
// via in-register 4-lane shfl reduce; query f16 fragments recovered from
// staged -2c tile by exact *(-0.5).
// Keys: quad = f32bits&~0xFF | qid(8b); member = f32bits&~0x3FF | idx(10b).
// MFMA 16x16x16f16, C operand carries |c|^2+128.

#define L_SEG 1024
#define M_PTS 65536

typedef __fp16 fp16x2 __attribute__((ext_vector_type(2)));
typedef __fp16 fp16x4 __attribute__((ext_vector_type(4)));
typedef float  f32x4  __attribute__((ext_vector_type(4)));

__device__ __forceinline__ uint32_t umn(uint32_t a, uint32_t b) { return a < b ? a : b; }
__device__ __forceinline__ uint32_t umx(uint32_t a, uint32_t b) { return a > b ? a : b; }

#define CE(arr, i, p) { uint32_t lo = umn(arr[i], arr[p]); uint32_t hi = umx(arr[i], arr[p]); arr[i] = lo; arr[p] = hi; }

// bitonic clean of 16 (input bitonic, output sorted ascending): 32 CEs
__device__ __forceinline__ void clean16(uint32_t* A) {
    #pragma unroll
    for (int j = 8; j > 0; j >>= 1) {
        #pragma unroll
        for (int i = 0; i < 16; ++i) {
            int p = i ^ j;
            if (p > i) CE(A, i, p);
        }
    }
}

// Batcher odd-even mergesort-16, ascending (63 CEs)
__device__ __forceinline__ void sort16(uint32_t* B) {
    #pragma unroll
    for (int p = 1; p < 16; p <<= 1) {
        #pragma unroll
        for (int k = p; k >= 1; k >>= 1) {
            #pragma unroll
            for (int j = (k & (p - 1)); j + k < 16; j += 2 * k) {
                #pragma unroll
                for (int i = 0; i <= ((k - 1 < 15 - j - k) ? k - 1 : 15 - j - k); ++i) {
                    if ((i + j) / (2 * p) == (i + j + k) / (2 * p)) CE(B, i + j, i + j + k);
                }
            }
        }
    }
}

// merge sorted S (descending-taken) into sorted A, keep lowest 16
__device__ __forceinline__ void keep16(uint32_t* A, const uint32_t* S) {
    #pragma unroll
    for (int i = 0; i < 16; ++i) A[i] = umn(A[i], S[15 - i]);
    clean16(A);
}

// cross-lane merges over g (xor 16 then 32): disjoint contents per lane
__device__ __forceinline__ void mergeg(uint32_t* A) {
    #pragma unroll
    for (int m = 16; m <= 32; m <<= 1) {
        uint32_t P[16];
        #pragma unroll
        for (int i = 0; i < 16; ++i) P[i] = (uint32_t)__shfl_xor((int)A[15 - i], m, 64);
        #pragma unroll
        for (int i = 0; i < 16; ++i) A[i] = umn(A[i], P[i]);
        clean16(A);
    }
}

__device__ __forceinline__ uint32_t sel4(const uint32_t* A, int g, int v) {
    uint32_t t01 = (g & 1) ? A[4 + v]  : A[v];
    uint32_t t23 = (g & 1) ? A[12 + v] : A[8 + v];
    return (g & 2) ? t23 : t01;
}

__global__ __launch_bounds__(1024, 1) void knn_v11_kernel(const float* __restrict__ x,
                                                          int* __restrict__ out) {
    __shared__ __attribute__((aligned(16))) __fp16 sc[L_SEG * 16];  // -2*c, [cand][dim], 32KB
    __shared__ __attribute__((aligned(16))) float  ssq[L_SEG];      // |c|^2 + 128 (f32), 4KB

    const int tid  = threadIdx.x;
    const int b    = blockIdx.x;
    const int seg  = b >> 2;          // 4 blocks per segment
    const int qgrp = (b & 3) << 8;    // 256 queries per block
    const float* xseg = x + (size_t)seg * (L_SEG * 16);
    const f32x4* gx4  = (const f32x4*)xseg;

    // ---- stage coords * -2 as f16 [cand][dim]; norms via 4-lane shfl reduce ----
    {
        fp16x4* scv = (fp16x4*)sc;
        #pragma unroll
        for (int i = 0; i < 4; ++i) {
            f32x4 v = gx4[tid + 1024 * i];            // coalesced: 16B/lane contiguous
            union { fp16x2 h2[2]; fp16x4 h4; } u;
            u.h2[0] = __builtin_amdgcn_cvt_pkrtz(-2.0f * v[0], -2.0f * v[1]);
            u.h2[1] = __builtin_amdgcn_cvt_pkrtz(-2.0f * v[2], -2.0f * v[3]);
            scv[tid + 1024 * i] = u.h4;
            // lanes t, t^1, t^2, t^3 hold the 4 dim-quads of cand (t>>2)+256i
            float p = v[0] * v[0];
            p = __builtin_fmaf(v[1], v[1], p);
            p = __builtin_fmaf(v[2], v[2], p);
            p = __builtin_fmaf(v[3], v[3], p);
            p += __shfl_xor(p, 1, 64);
            p += __shfl_xor(p, 2, 64);
            if ((tid & 3) == 0) ssq[(tid >> 2) + 256 * i] = p + 128.0f;
        }
    }
    __syncthreads();

    const int lane = tid & 63;
    const int w    = tid >> 6;        // wave 0..15
    const int g    = lane >> 4;       // lane owns quad (tilequad + g)
    const int col  = lane & 15;       // query column
    const int qrow = qgrp + w * 16 + col;   // query local index in segment

    const fp16x4 mh = {(__fp16)-0.5f, (__fp16)-0.5f, (__fp16)-0.5f, (__fp16)-0.5f};
    // B fragment: rtz(q) recovered exactly from staged rtz(-2q) via *(-0.5)
    fp16x4 bfrag;
    {
        fp16x4 raw = *(const fp16x4*)(sc + (size_t)qrow * 16 + g * 4);
        bfrag = raw * mh;
    }

    const __fp16* ap  = sc + (size_t)col * 16 + g * 4;   // + cand*16 halves
    const float*  sqp = ssq + g * 4;

    uint32_t A[16];
    {   // iter 0: A = sorted(P) directly (keep16 vs +inf is a copy)
        uint32_t P[16];
        #pragma unroll
        for (int t = 0; t < 16; ++t) {
            const int cb = t * 16;
            fp16x4 af = *(const fp16x4*)(ap + (size_t)cb * 16);
            f32x4  sq = *(const f32x4*)(sqp + cb);
            f32x4 acc = __builtin_amdgcn_mfma_f32_16x16x16f16(af, bfrag, sq, 0, 0, 0);
            float m = fminf(fminf(fminf(acc[0], acc[1]), acc[2]), acc[3]);
            P[t] = (__float_as_uint(m) & 0xFFFFFF00u) | (uint32_t)(t * 4) | (uint32_t)g;
        }
        sort16(P);
        #pragma unroll
        for (int i = 0; i < 16; ++i) A[i] = P[i];
    }
    #pragma unroll
    for (int it = 1; it < 4; ++it) {
        uint32_t P[16];
        #pragma unroll
        for (int t = 0; t < 16; ++t) {
            const int cb = it * 256 + t * 16;
            fp16x4 af = *(const fp16x4*)(ap + (size_t)cb * 16);
            f32x4  sq = *(const f32x4*)(sqp + cb);
            f32x4 acc = __builtin_amdgcn_mfma_f32_16x16x16f16(af, bfrag, sq, 0, 0, 0);
            float m = fminf(fminf(fminf(acc[0], acc[1]), acc[2]), acc[3]);
            P[t] = (__float_as_uint(m) & 0xFFFFFF00u) | (uint32_t)(it * 64 + t * 4) | (uint32_t)g;
        }
        sort16(P);
        keep16(A, P);
    }

    mergeg(A);  // all 4 g-lanes: identical sorted top-16 quad keys (of 256 quads)

    // ---- repair: lane g evaluates ALL 4 members of winners 4g..4g+3 ----
    union H8 { f32x4 v[2]; fp16x4 h4[2]; fp16x2 h2[8]; };
    H8 qq;
    {
        const f32x4* qf = (const f32x4*)(sc + (size_t)qrow * 16);
        qq.v[0] = qf[0]; qq.v[1] = qf[1];
        qq.h4[0] = qq.h4[0] * mh;    // exact: q from -2q
        qq.h4[1] = qq.h4[1] * mh;
    }
    uint32_t R[16];
    #pragma unroll
    for (int v = 0; v < 4; ++v) {
        const uint32_t qid   = sel4(A, g, v) & 255u;
        const uint32_t pbase = qid << 2;
        #pragma unroll
        for (int m = 0; m < 4; ++m) {
            const uint32_t pidx = pbase + (uint32_t)m;
            H8 cc;
            const f32x4* cf = (const f32x4*)(sc + (size_t)pidx * 16);  // -2*c
            cc.v[0] = cf[0]; cc.v[1] = cf[1];
            float s = ssq[pidx];           // |p|^2 + 128, then accumulate -2<p,q>
            #pragma unroll
            for (int j = 0; j < 8; ++j) {
#if __has_builtin(__builtin_amdgcn_fdot2)
                s = __builtin_amdgcn_fdot2(cc.h2[j], qq.h2[j], s, false);
#else
                s = __builtin_fmaf((float)cc.h2[j][0], (float)qq.h2[j][0], s);
                s = __builtin_fmaf((float)cc.h2[j][1], (float)qq.h2[j][1], s);
#endif
            }
            R[v * 4 + m] = (__float_as_uint(s) & 0xFFFFFC00u) | pidx;
        }
    }
    sort16(R);
    mergeg(R);  // 64 member-distances across g-lanes -> exact final top-16, all lanes equal

    // ---- epilogue: lane (g,col) writes int4 #g of src and dst for its query ----
    const int base = seg * L_SEG;
    const int q    = base + qrow;
    int4 sv;
    sv.x = base + (int)(sel4(R, g, 0) & 1023u);
    sv.y = base + (int)(sel4(R, g, 1) & 1023u);
    sv.z = base + (int)(sel4(R, g, 2) & 1023u);
    sv.w = base + (int)(sel4(R, g, 3) & 1023u);
    ((int4*)out)[(size_t)q * 4 + g] = sv;
    ((int4*)out)[(size_t)M_PTS * 4 + (size_t)q * 4 + g] = make_int4(q, q, q, q);
}

extern "C" void kernel_launch(void* const* d_in, const int* in_sizes, int n_in,
                              void* d_out, int out_size, void* d_ws, size_t ws_size,
                              hipStream_t stream) {
    const float* x = (const float*)d_in[0];
    // d_in[1] = segs (int64, all 1024) — static per problem setup, unused.
    int* out = (int*)d_out;
    (void)d_ws; (void)ws_size;
    knn_v11_kernel<<<dim3(256), dim3(1024), 0, stream>>>(x, out);
}

// Round 3
// 78.021 us; speedup vs baseline: 1.1003x; 1.1003x over previous
//
#include <hip/hip_runtime.h>
#include <stdint.h>

// Segmented kNN graph: M=65536 pts, D=16, 64 segments x 1024 pts, K=16.
// Output: int32 src[M*16] then int32 dst[M*16].
//
// v12 = v11 with the repair phase rewritten as 4 MFMA tiles.
// Evidence: v10 rocprof SQ_LDS_BANK_CONFLICT=7.4M cyc (~12us/CU of LDS
// stall); audit shows main-loop af reads are contiguous-512B (clean) and
// the conflicts come from repair's 32 scattered ds_read_b128/lane
// (pidx*32B -> 4 bank-groups, up to 16-way) + 16 scattered ssq gathers.
// After mergeg(A) all 64 lanes hold the SAME 16 winning quads = 64 shared
// members, so repair = 4 more 16x16x16 MFMA tiles: A-rows gathered by
// wave-uniform member index (2 cndmask selects/lane, no shuffles),
// ds_read_b64 4-way worst; C-operand = contiguous ssq b128 per quad
// (quad members are contiguous cands). Replaces ~180 VALU + 48 scattered
// DS with ~85 VALU + 8 DS + 4 MFMA, and makes repair distances
// bit-identical to main-loop distances (same MFMA path).
//
// Carried from v11: quad-id keys (f32 quad-min via min3+min, 8-bit qid tag);
// top-16 of R alone is exact (R = all 64 members of top-16 quads);
// iter-0 A=sorted(P); 1024-thr blocks, 256 queries/block, grid=256;
// __launch_bounds__(1024,1) (16 waves/CU, 128-VGPR cap — (1024,4) spilled);
// norms via 4-lane shfl reduce; query f16 recovered from -2c tile by *(-0.5).
// Keys: quad = f32bits&~0xFF | qid(8b); member = f32bits&~0x3FF | idx(10b).
// MFMA 16x16x16f16, C operand carries |c|^2+128.

#define L_SEG 1024
#define M_PTS 65536

typedef __fp16 fp16x2 __attribute__((ext_vector_type(2)));
typedef __fp16 fp16x4 __attribute__((ext_vector_type(4)));
typedef float  f32x4  __attribute__((ext_vector_type(4)));

__device__ __forceinline__ uint32_t umn(uint32_t a, uint32_t b) { return a < b ? a : b; }
__device__ __forceinline__ uint32_t umx(uint32_t a, uint32_t b) { return a > b ? a : b; }

#define CE(arr, i, p) { uint32_t lo = umn(arr[i], arr[p]); uint32_t hi = umx(arr[i], arr[p]); arr[i] = lo; arr[p] = hi; }

// bitonic clean of 16 (input bitonic, output sorted ascending): 32 CEs
__device__ __forceinline__ void clean16(uint32_t* A) {
    #pragma unroll
    for (int j = 8; j > 0; j >>= 1) {
        #pragma unroll
        for (int i = 0; i < 16; ++i) {
            int p = i ^ j;
            if (p > i) CE(A, i, p);
        }
    }
}

// Batcher odd-even mergesort-16, ascending (63 CEs)
__device__ __forceinline__ void sort16(uint32_t* B) {
    #pragma unroll
    for (int p = 1; p < 16; p <<= 1) {
        #pragma unroll
        for (int k = p; k >= 1; k >>= 1) {
            #pragma unroll
            for (int j = (k & (p - 1)); j + k < 16; j += 2 * k) {
                #pragma unroll
                for (int i = 0; i <= ((k - 1 < 15 - j - k) ? k - 1 : 15 - j - k); ++i) {
                    if ((i + j) / (2 * p) == (i + j + k) / (2 * p)) CE(B, i + j, i + j + k);
                }
            }
        }
    }
}

// merge sorted S (descending-taken) into sorted A, keep lowest 16
__device__ __forceinline__ void keep16(uint32_t* A, const uint32_t* S) {
    #pragma unroll
    for (int i = 0; i < 16; ++i) A[i] = umn(A[i], S[15 - i]);
    clean16(A);
}

// cross-lane merges over g (xor 16 then 32): disjoint contents per lane
__device__ __forceinline__ void mergeg(uint32_t* A) {
    #pragma unroll
    for (int m = 16; m <= 32; m <<= 1) {
        uint32_t P[16];
        #pragma unroll
        for (int i = 0; i < 16; ++i) P[i] = (uint32_t)__shfl_xor((int)A[15 - i], m, 64);
        #pragma unroll
        for (int i = 0; i < 16; ++i) A[i] = umn(A[i], P[i]);
        clean16(A);
    }
}

__device__ __forceinline__ uint32_t sel4(const uint32_t* A, int g, int v) {
    uint32_t t01 = (g & 1) ? A[4 + v]  : A[v];
    uint32_t t23 = (g & 1) ? A[12 + v] : A[8 + v];
    return (g & 2) ? t23 : t01;
}

__global__ __launch_bounds__(1024, 1) void knn_v12_kernel(const float* __restrict__ x,
                                                          int* __restrict__ out) {
    __shared__ __attribute__((aligned(16))) __fp16 sc[L_SEG * 16];  // -2*c, [cand][dim], 32KB
    __shared__ __attribute__((aligned(16))) float  ssq[L_SEG];      // |c|^2 + 128 (f32), 4KB

    const int tid  = threadIdx.x;
    const int b    = blockIdx.x;
    const int seg  = b >> 2;          // 4 blocks per segment
    const int qgrp = (b & 3) << 8;    // 256 queries per block
    const float* xseg = x + (size_t)seg * (L_SEG * 16);
    const f32x4* gx4  = (const f32x4*)xseg;

    // ---- stage coords * -2 as f16 [cand][dim]; norms via 4-lane shfl reduce ----
    {
        fp16x4* scv = (fp16x4*)sc;
        #pragma unroll
        for (int i = 0; i < 4; ++i) {
            f32x4 v = gx4[tid + 1024 * i];            // coalesced: 16B/lane contiguous
            union { fp16x2 h2[2]; fp16x4 h4; } u;
            u.h2[0] = __builtin_amdgcn_cvt_pkrtz(-2.0f * v[0], -2.0f * v[1]);
            u.h2[1] = __builtin_amdgcn_cvt_pkrtz(-2.0f * v[2], -2.0f * v[3]);
            scv[tid + 1024 * i] = u.h4;
            // lanes t, t^1, t^2, t^3 hold the 4 dim-quads of cand (t>>2)+256i
            float p = v[0] * v[0];
            p = __builtin_fmaf(v[1], v[1], p);
            p = __builtin_fmaf(v[2], v[2], p);
            p = __builtin_fmaf(v[3], v[3], p);
            p += __shfl_xor(p, 1, 64);
            p += __shfl_xor(p, 2, 64);
            if ((tid & 3) == 0) ssq[(tid >> 2) + 256 * i] = p + 128.0f;
        }
    }
    __syncthreads();

    const int lane = tid & 63;
    const int w    = tid >> 6;        // wave 0..15
    const int g    = lane >> 4;       // lane owns quad (tilequad + g)
    const int col  = lane & 15;       // query column
    const int qrow = qgrp + w * 16 + col;   // query local index in segment

    const fp16x4 mh = {(__fp16)-0.5f, (__fp16)-0.5f, (__fp16)-0.5f, (__fp16)-0.5f};
    // B fragment: rtz(q) recovered exactly from staged rtz(-2q) via *(-0.5)
    fp16x4 bfrag;
    {
        fp16x4 raw = *(const fp16x4*)(sc + (size_t)qrow * 16 + g * 4);
        bfrag = raw * mh;
    }

    const __fp16* ap  = sc + (size_t)col * 16 + g * 4;   // + cand*16 halves
    const float*  sqp = ssq + g * 4;

    uint32_t A[16];
    {   // iter 0: A = sorted(P) directly (keep16 vs +inf is a copy)
        uint32_t P[16];
        #pragma unroll
        for (int t = 0; t < 16; ++t) {
            const int cb = t * 16;
            fp16x4 af = *(const fp16x4*)(ap + (size_t)cb * 16);
            f32x4  sq = *(const f32x4*)(sqp + cb);
            f32x4 acc = __builtin_amdgcn_mfma_f32_16x16x16f16(af, bfrag, sq, 0, 0, 0);
            float m = fminf(fminf(fminf(acc[0], acc[1]), acc[2]), acc[3]);
            P[t] = (__float_as_uint(m) & 0xFFFFFF00u) | (uint32_t)(t * 4) | (uint32_t)g;
        }
        sort16(P);
        #pragma unroll
        for (int i = 0; i < 16; ++i) A[i] = P[i];
    }
    #pragma unroll
    for (int it = 1; it < 4; ++it) {
        uint32_t P[16];
        #pragma unroll
        for (int t = 0; t < 16; ++t) {
            const int cb = it * 256 + t * 16;
            fp16x4 af = *(const fp16x4*)(ap + (size_t)cb * 16);
            f32x4  sq = *(const f32x4*)(sqp + cb);
            f32x4 acc = __builtin_amdgcn_mfma_f32_16x16x16f16(af, bfrag, sq, 0, 0, 0);
            float m = fminf(fminf(fminf(acc[0], acc[1]), acc[2]), acc[3]);
            P[t] = (__float_as_uint(m) & 0xFFFFFF00u) | (uint32_t)(it * 64 + t * 4) | (uint32_t)g;
        }
        sort16(P);
        keep16(A, P);
    }

    mergeg(A);  // all lanes now hold the IDENTICAL sorted top-16 quad keys

    // ---- repair via MFMA: distances of all 64 winner-members x 16 queries ----
    // Tile j covers winners A[4j..4j+3]; member row r of tile j is cand
    // (A[4j + (r>>2)] & 255)*4 + (r&3). A is wave-uniform -> each lane
    // computes its own member index with cndmask selects, no shuffles.
    uint32_t R[16];
    {
        const uint32_t c2a = (uint32_t)(col & 4);   // (col>>2)&1
        const uint32_t c2b = (uint32_t)(col & 8);   // (col>>2)&2
        const uint32_t v0  = (uint32_t)(col & 3);
        #pragma unroll
        for (int j = 0; j < 4; ++j) {
            // A-operand: row = col -> member index from A[4j + (col>>2)]
            const uint32_t t01 = c2a ? A[4*j + 1] : A[4*j + 0];
            const uint32_t t23 = c2a ? A[4*j + 3] : A[4*j + 2];
            const uint32_t awc = c2b ? t23 : t01;
            const uint32_t mrow = ((awc & 255u) << 2) | v0;
            fp16x4 af = *(const fp16x4*)(sc + (size_t)mrow * 16 + g * 4);
            // C-operand + key base: rows 4g..4g+3 -> quad A[4j + g]
            const uint32_t u01 = (g & 1) ? A[4*j + 1] : A[4*j + 0];
            const uint32_t u23 = (g & 1) ? A[4*j + 3] : A[4*j + 2];
            const uint32_t awg = (g & 2) ? u23 : u01;
            const uint32_t ib  = (awg & 255u) << 2;          // first member cand
            f32x4 sq = *(const f32x4*)(ssq + (size_t)ib);    // contiguous b128
            f32x4 acc = __builtin_amdgcn_mfma_f32_16x16x16f16(af, bfrag, sq, 0, 0, 0);
            R[j*4 + 0] = (__float_as_uint(acc[0]) & 0xFFFFFC00u) | ib;
            R[j*4 + 1] = (__float_as_uint(acc[1]) & 0xFFFFFC00u) | (ib + 1u);
            R[j*4 + 2] = (__float_as_uint(acc[2]) & 0xFFFFFC00u) | (ib + 2u);
            R[j*4 + 3] = (__float_as_uint(acc[3]) & 0xFFFFFC00u) | (ib + 3u);
        }
    }
    sort16(R);
    mergeg(R);  // 64 member-distances across g-lanes -> exact final top-16, all lanes equal

    // ---- epilogue: lane (g,col) writes int4 #g of src and dst for its query ----
    const int base = seg * L_SEG;
    const int q    = base + qrow;
    int4 sv;
    sv.x = base + (int)(sel4(R, g, 0) & 1023u);
    sv.y = base + (int)(sel4(R, g, 1) & 1023u);
    sv.z = base + (int)(sel4(R, g, 2) & 1023u);
    sv.w = base + (int)(sel4(R, g, 3) & 1023u);
    ((int4*)out)[(size_t)q * 4 + g] = sv;
    ((int4*)out)[(size_t)M_PTS * 4 + (size_t)q * 4 + g] = make_int4(q, q, q, q);
}

extern "C" void kernel_launch(void* const* d_in, const int* in_sizes, int n_in,
                              void* d_out, int out_size, void* d_ws, size_t ws_size,
                              hipStream_t stream) {
    const float* x = (const float*)d_in[0];
    // d_in[1] = segs (int64, all 1024) — static per problem setup, unused.
    int* out = (int*)d_out;
    (void)d_ws; (void)ws_size;
    knn_v12_kernel<<<dim3(256), dim3(1024), 0, stream>>>(x, out);
}